// Round 17
// baseline (187.643 us; speedup 1.0000x reference)
//
#include <hip/hip_runtime.h>
#include <cstdint>
#include <cstddef>

typedef _Float16 half8 __attribute__((ext_vector_type(8)));
typedef _Float16 half4 __attribute__((ext_vector_type(4)));
typedef float f32x4 __attribute__((ext_vector_type(4)));

#define MFMA16(A,B,C) __builtin_amdgcn_mfma_f32_16x16x32_f16(A,B,C,0,0,0)

// ---------------- K0: bulk f32 -> f16 convert (X, Wi, Wo) ----------------
__global__ __launch_bounds__(256) void cvt_f16(
    const float* __restrict__ X, const float* __restrict__ Wi, const float* __restrict__ Wo,
    _Float16* __restrict__ Xh, _Float16* __restrict__ Wih, _Float16* __restrict__ Woh)
{
    const size_t i8 = ((size_t)blockIdx.x * 256 + threadIdx.x) * 8;
    const size_t NX = (size_t)4194304, NWI = 786432;
    const float* src; _Float16* dst; size_t off;
    if (i8 < NX) { src = X; dst = Xh; off = i8; }
    else if (i8 < NX + NWI) { src = Wi; dst = Wih; off = i8 - NX; }
    else { src = Wo; dst = Woh; off = i8 - NX - NWI; }
    f32x4 v0 = *(const f32x4*)(src + off);
    f32x4 v1 = *(const f32x4*)(src + off + 4);
    half8 r;
    r[0]=(_Float16)v0[0]; r[1]=(_Float16)v0[1]; r[2]=(_Float16)v0[2]; r[3]=(_Float16)v0[3];
    r[4]=(_Float16)v1[0]; r[5]=(_Float16)v1[1]; r[6]=(_Float16)v1[2]; r[7]=(_Float16)v1[3];
    *(half8*)(dst + off) = r;
}

// ---------------- K1: QKV projection (f16 MFMA, f16 inputs) ----------------
// V^T written PRE-PERMUTED within each 32-col group: s -> (s&~31)|8g|4hi|j
__global__ __launch_bounds__(256) void qkv_mfma(
    const _Float16* __restrict__ X, const _Float16* __restrict__ W,
    const float* __restrict__ bias, const float* __restrict__ gate,
    _Float16* __restrict__ Qo, _Float16* __restrict__ Ko, _Float16* __restrict__ Vt)
{
    __shared__ _Float16 As[128][72];
    __shared__ _Float16 Bs[64][72];
    const int tid = threadIdx.x;
    const int lane = tid & 63, wv = tid >> 6;
    const int l15 = lane & 15, g = lane >> 4;
    const int wr = wv >> 1, wc = wv & 1;
    const int j0 = blockIdx.x * 64, r0 = blockIdx.y * 128;
    f32x4 acc[4][2] = {};
    const int arow = tid >> 1, ahf = tid & 1;
    const int brow = tid >> 2, bc = tid & 3;
    for (int k0 = 0; k0 < 512; k0 += 64) {
        const _Float16* srca = X + (size_t)(r0 + arow) * 512 + k0 + ahf * 32;
#pragma unroll
        for (int c = 0; c < 4; ++c)
            *(half8*)&As[arow][ahf * 32 + c * 8] = *(const half8*)(srca + c * 8);
        const _Float16* srcb = W + (size_t)(j0 + brow) * 512 + k0 + bc * 16;
#pragma unroll
        for (int c = 0; c < 2; ++c)
            *(half8*)&Bs[brow][bc * 16 + c * 8] = *(const half8*)(srcb + c * 8);
        __syncthreads();
#pragma unroll
        for (int kt = 0; kt < 2; ++kt) {
            half8 bf0 = *(half8*)&Bs[32 * wc + l15][kt * 32 + g * 8];
            half8 bf1 = *(half8*)&Bs[32 * wc + 16 + l15][kt * 32 + g * 8];
#pragma unroll
            for (int ri = 0; ri < 4; ++ri) {
                half8 af = *(half8*)&As[64 * wr + 16 * ri + l15][kt * 32 + g * 8];
                acc[ri][0] = MFMA16(af, bf0, acc[ri][0]);
                acc[ri][1] = MFMA16(af, bf1, acc[ri][1]);
            }
        }
        __syncthreads();
    }
#pragma unroll
    for (int ri = 0; ri < 4; ++ri) {
#pragma unroll
        for (int cj = 0; cj < 2; ++cj) {
            const int col = j0 + 32 * wc + 16 * cj + l15;
            const int sec = col >> 9, hh = (col >> 6) & 7, d = col & 63;
            const float bv = bias[col];
#pragma unroll
            for (int r = 0; r < 4; ++r) {
                const int row = r0 + 64 * wr + 16 * ri + 4 * g + r;
                const int b = row & 3, s = row >> 2;
                const float v = acc[ri][cj][r];
                if (sec == 0)
                    Qo[((size_t)(b * 8 + hh) * 2048 + s) * 64 + d] = (_Float16)((v + bv) * 0.125f);
                else if (sec == 1)
                    Ko[((size_t)(b * 8 + hh) * 2048 + s) * 64 + d] = (_Float16)(v + bv);
                else {
                    const int ps = (s & ~31) | ((s & 12) << 1) | ((s & 16) >> 2) | (s & 3);
                    Vt[((size_t)(b * 8 + hh) * 64 + d) * 2048 + ps] = (_Float16)(v * gate[b] + bv);
                }
            }
        }
    }
}

// ---------------- K2: flash attention, NO LDS / NO BARRIERS, direct-to-reg ----------
// Block = 256 thr (4 waves); wave w = batch w, 64 q-rows, one kv-half.
// Every operand (K frags, V frags, mask C-init) loads straight from global:
// waves are fully independent and drift freely -> phases of different waves
// overlap (mask HBM under one wave hides under another wave's MFMA/VALU).
// XCD-aware bid: blocks sharing (h,kvh) [same K/V slice, ~2 MB] land on one
// XCD's L2. Pre-permuted Vt makes vf a contiguous half8 (no swizzle).
__global__ __launch_bounds__(256) void attn_mfma(
    const _Float16* __restrict__ Q, const _Float16* __restrict__ K,
    const _Float16* __restrict__ V, const float* __restrict__ M,
    _Float16* __restrict__ P0, _Float16* __restrict__ P1, float* __restrict__ Lb)
{
    const int tid = threadIdx.x;
    const int lane = tid & 63, w = tid >> 6;
    const int l15 = lane & 15, g = lane >> 4;
    // bid = xcd + 8*(qg + 32*hi); idx = xcd + 8*hi selects (h,kvh)
    const int bid = blockIdx.x;
    const int xcd = bid & 7, s = bid >> 3;
    const int qg = s & 31, hi = s >> 5;
    const int idx = xcd + 8 * hi;
    const int h = idx >> 1, kvh = idx & 1;
    const int q0 = qg * 64;
    const int b = w;
    const size_t bh = (size_t)b * 8 + h;
    const _Float16* Qp = Q + bh * 2048 * 64;
    const _Float16* Kp = K + (bh * 2048 + (size_t)kvh * 1024) * 64;
    const _Float16* Vp = V + bh * 64 * 2048 + kvh * 1024;   // permuted [d][s]
    const float* Mp = M + (size_t)h * 2048 * 2048 + kvh * 1024;

    // Q fragments: 64 q-rows of batch b (pre-scaled by 1/8 in qkv)
    half8 qf[4][2];
#pragma unroll
    for (int qj = 0; qj < 4; ++qj)
#pragma unroll
        for (int dh = 0; dh < 2; ++dh)
            qf[qj][dh] = *(const half8*)(Qp + (size_t)(q0 + 16 * qj + l15) * 64 + dh * 32 + g * 8);

    f32x4 O[4][4] = {};   // [di][qj]
    float l[4] = {0.f, 0.f, 0.f, 0.f};

    for (int tl = 0; tl < 32; ++tl) {
        const int t0 = tl * 32;
        half8 pf[4];
        // QK^T in two mi phases (16 kv rows each); mask JIT as MFMA C-init
#pragma unroll
        for (int mi = 0; mi < 2; ++mi) {
            const _Float16* kr = Kp + (size_t)(t0 + 16 * mi + l15) * 64 + g * 8;
            half8 kf0 = *(const half8*)(kr);
            half8 kf1 = *(const half8*)(kr + 32);
            f32x4 St[4];
#pragma unroll
            for (int qj = 0; qj < 4; ++qj) {
                const f32x4 ci = *(const f32x4*)
                    (Mp + (size_t)(q0 + 16 * qj + l15) * 2048 + t0 + 16 * mi + 4 * g);
                St[qj] = MFMA16(kf0, qf[qj][0], ci);
                St[qj] = MFMA16(kf1, qf[qj][1], St[qj]);
            }
            // static softmax partials; pf k-slots {4g+j} (mi=0) / {16+4g+j} (mi=1)
#pragma unroll
            for (int qj = 0; qj < 4; ++qj) {
                float e0 = __expf(St[qj][0]), e1 = __expf(St[qj][1]);
                float e2 = __expf(St[qj][2]), e3 = __expf(St[qj][3]);
                l[qj] += (e0 + e1) + (e2 + e3);
                pf[qj][4 * mi + 0] = (_Float16)e0; pf[qj][4 * mi + 1] = (_Float16)e1;
                pf[qj][4 * mi + 2] = (_Float16)e2; pf[qj][4 * mi + 3] = (_Float16)e3;
            }
        }
        // PV: vf contiguous from pre-permuted Vt
#pragma unroll
        for (int di = 0; di < 4; ++di) {
            half8 vf = *(const half8*)(Vp + (size_t)(16 * di + l15) * 2048 + t0 + g * 8);
#pragma unroll
            for (int qj = 0; qj < 4; ++qj)
                O[di][qj] = MFMA16(vf, pf[qj], O[di][qj]);
        }
    }

    // epilogue: per q-subtile, reduce l across g, write normalized partial + l
    _Float16* P = kvh ? P1 : P0;
#pragma unroll
    for (int qj = 0; qj < 4; ++qj) {
        float lt = l[qj];
        lt += __shfl_xor(lt, 16);
        lt += __shfl_xor(lt, 32);
        const float inv = 1.0f / lt;
        const int q = q0 + 16 * qj + l15;
        const int r = q * 4 + b;
        _Float16* dst = P + (size_t)r * 512 + h * 64;
#pragma unroll
        for (int di = 0; di < 4; ++di) {
            half4 o;
            o[0] = (_Float16)(O[di][qj][0] * inv); o[1] = (_Float16)(O[di][qj][1] * inv);
            o[2] = (_Float16)(O[di][qj][2] * inv); o[3] = (_Float16)(O[di][qj][3] * inv);
            *(half4*)(dst + 16 * di + 4 * g) = o;
        }
        if (g == 0)
            Lb[(size_t)kvh * 65536 + r * 8 + h] = lt;
    }
}

// ---------------- K2b: merge the two kv-half partials (raw-l weights) ------------
__global__ __launch_bounds__(256) void merge_attn(
    const _Float16* __restrict__ P0, const _Float16* __restrict__ P1,
    const float* __restrict__ Lb, _Float16* __restrict__ AO)
{
    const size_t e = ((size_t)blockIdx.x * 256 + threadIdx.x) * 8;
    const int r = (int)(e >> 9);
    const int h = (int)((e & 511) >> 6);
    const int li = r * 8 + h;
    const float l0 = Lb[li], l1 = Lb[65536 + li];
    const float inv = 1.0f / (l0 + l1);
    const float a0 = l0 * inv, a1 = l1 * inv;
    half8 x0 = *(const half8*)(P0 + e);
    half8 x1 = *(const half8*)(P1 + e);
    half8 o;
#pragma unroll
    for (int i = 0; i < 8; ++i)
        o[i] = (_Float16)(a0 * (float)x0[i] + a1 * (float)x1[i]);
    *(half8*)(AO + e) = o;
}

// ---------------- K3: output projection (f16 inputs, f32 out) ----------------
__global__ __launch_bounds__(256) void oproj_mfma(
    const _Float16* __restrict__ A, const _Float16* __restrict__ W,
    const float* __restrict__ bias, float* __restrict__ Out)
{
    __shared__ _Float16 As[128][72];
    __shared__ _Float16 Bs[64][72];
    const int tid = threadIdx.x;
    const int lane = tid & 63, wv = tid >> 6;
    const int l15 = lane & 15, g = lane >> 4;
    const int wr = wv >> 1, wc = wv & 1;
    const int j0 = blockIdx.x * 64, r0 = blockIdx.y * 128;
    f32x4 acc[4][2] = {};
    const int arow = tid >> 1, ahf = tid & 1;
    const int brow = tid >> 2, bc = tid & 3;
    for (int k0 = 0; k0 < 512; k0 += 64) {
        const _Float16* srca = A + (size_t)(r0 + arow) * 512 + k0 + ahf * 32;
#pragma unroll
        for (int c = 0; c < 4; ++c)
            *(half8*)&As[arow][ahf * 32 + c * 8] = *(const half8*)(srca + c * 8);
        const _Float16* srcb = W + (size_t)(j0 + brow) * 512 + k0 + bc * 16;
#pragma unroll
        for (int c = 0; c < 2; ++c)
            *(half8*)&Bs[brow][bc * 16 + c * 8] = *(const half8*)(srcb + c * 8);
        __syncthreads();
#pragma unroll
        for (int kt = 0; kt < 2; ++kt) {
            half8 bf0 = *(half8*)&Bs[32 * wc + l15][kt * 32 + g * 8];
            half8 bf1 = *(half8*)&Bs[32 * wc + 16 + l15][kt * 32 + g * 8];
#pragma unroll
            for (int ri = 0; ri < 4; ++ri) {
                half8 af = *(half8*)&As[64 * wr + 16 * ri + l15][kt * 32 + g * 8];
                acc[ri][0] = MFMA16(af, bf0, acc[ri][0]);
                acc[ri][1] = MFMA16(af, bf1, acc[ri][1]);
            }
        }
        __syncthreads();
    }
#pragma unroll
    for (int ri = 0; ri < 4; ++ri) {
#pragma unroll
        for (int cj = 0; cj < 2; ++cj) {
            const int col = j0 + 32 * wc + 16 * cj + l15;
            const float bv = bias[col];
#pragma unroll
            for (int r = 0; r < 4; ++r) {
                const int row = r0 + 64 * wr + 16 * ri + 4 * g + r;
                Out[(size_t)row * 512 + col] = acc[ri][cj][r] + bv;
            }
        }
    }
}

extern "C" void kernel_launch(void* const* d_in, const int* in_sizes, int n_in,
                              void* d_out, int out_size, void* d_ws, size_t ws_size,
                              hipStream_t stream)
{
    (void)in_sizes; (void)n_in; (void)out_size; (void)ws_size;
    const float* X    = (const float*)d_in[0];  // (S,B,D)
    const float* Mask = (const float*)d_in[1];  // (H,S,S)
    const float* gate = (const float*)d_in[2];  // (1,B,1)
    const float* Wi   = (const float*)d_in[3];  // (3D,D)
    const float* bi   = (const float*)d_in[4];  // (3D)
    const float* Wo   = (const float*)d_in[5];  // (D,D)
    const float* bo   = (const float*)d_in[6];  // (D)
    _Float16* ws = (_Float16*)d_ws;
    const size_t plane = (size_t)4 * 8 * 2048 * 64;  // 4,194,304 f16 elems
    _Float16* Qh  = ws;
    _Float16* Kh  = ws + plane;
    _Float16* Vt  = ws + 2 * plane;              // pre-permuted V^T
    _Float16* AO  = ws + 3 * plane;
    _Float16* Xh  = ws + 4 * plane;              // dead after qkv; aliased by P0
    _Float16* Wih = ws + 5 * plane;              // 786,432 (dead after qkv)
    _Float16* Woh = ws + 5 * plane + 786432;     // 262,144 (live until oproj)
    _Float16* P0  = Xh;
    _Float16* P1  = ws + 5 * plane + 1048576;
    float*    Lb  = (float*)(P1 + plane);        // 2*65536 f32

    cvt_f16<<<dim3(2560), 256, 0, stream>>>(X, Wi, Wo, Xh, Wih, Woh);
    qkv_mfma<<<dim3(24, 64), 256, 0, stream>>>(Xh, Wih, bi, gate, Qh, Kh, Vt);
    attn_mfma<<<dim3(512), 256, 0, stream>>>(Qh, Kh, Vt, Mask, P0, P1, Lb);
    merge_attn<<<dim3(2048), 256, 0, stream>>>(P0, P1, Lb, AO);
    oproj_mfma<<<dim3(8, 64), 256, 0, stream>>>(AO, Woh, bo, (float*)d_out);
}

// Round 18
// 118.694 us; speedup vs baseline: 1.5809x; 1.5809x over previous
//
#include <hip/hip_runtime.h>
#include <cstdint>
#include <cstddef>

typedef _Float16 half8 __attribute__((ext_vector_type(8)));
typedef _Float16 half4 __attribute__((ext_vector_type(4)));
typedef float f32x4 __attribute__((ext_vector_type(4)));

#define MFMA16(A,B,C) __builtin_amdgcn_mfma_f32_16x16x32_f16(A,B,C,0,0,0)

// global -> LDS direct copy, 16B per lane: lds dest = uniform base + lane*16,
// global source is PER-LANE.
__device__ __forceinline__ void gll16(const void* g, void* l) {
    __builtin_amdgcn_global_load_lds(
        (const __attribute__((address_space(1))) void*)g,
        (__attribute__((address_space(3))) void*)l, 16, 0, 0);
}

// ---------------- K0: bulk f32 -> f16 convert (X, Wi, Wo) ----------------
__global__ __launch_bounds__(256) void cvt_f16(
    const float* __restrict__ X, const float* __restrict__ Wi, const float* __restrict__ Wo,
    _Float16* __restrict__ Xh, _Float16* __restrict__ Wih, _Float16* __restrict__ Woh)
{
    const size_t i8 = ((size_t)blockIdx.x * 256 + threadIdx.x) * 8;
    const size_t NX = (size_t)4194304, NWI = 786432;
    const float* src; _Float16* dst; size_t off;
    if (i8 < NX) { src = X; dst = Xh; off = i8; }
    else if (i8 < NX + NWI) { src = Wi; dst = Wih; off = i8 - NX; }
    else { src = Wo; dst = Woh; off = i8 - NX - NWI; }
    f32x4 v0 = *(const f32x4*)(src + off);
    f32x4 v1 = *(const f32x4*)(src + off + 4);
    half8 r;
    r[0]=(_Float16)v0[0]; r[1]=(_Float16)v0[1]; r[2]=(_Float16)v0[2]; r[3]=(_Float16)v0[3];
    r[4]=(_Float16)v1[0]; r[5]=(_Float16)v1[1]; r[6]=(_Float16)v1[2]; r[7]=(_Float16)v1[3];
    *(half8*)(dst + off) = r;
}

// ---------------- K1: QKV projection (f16 MFMA, f16 inputs) ----------------
// V^T written PRE-PERMUTED within each 32-col group: s -> (s&~31)|8g|4hi|j
__global__ __launch_bounds__(256) void qkv_mfma(
    const _Float16* __restrict__ X, const _Float16* __restrict__ W,
    const float* __restrict__ bias, const float* __restrict__ gate,
    _Float16* __restrict__ Qo, _Float16* __restrict__ Ko, _Float16* __restrict__ Vt)
{
    __shared__ _Float16 As[128][72];
    __shared__ _Float16 Bs[64][72];
    const int tid = threadIdx.x;
    const int lane = tid & 63, wv = tid >> 6;
    const int l15 = lane & 15, g = lane >> 4;
    const int wr = wv >> 1, wc = wv & 1;
    const int j0 = blockIdx.x * 64, r0 = blockIdx.y * 128;
    f32x4 acc[4][2] = {};
    const int arow = tid >> 1, ahf = tid & 1;
    const int brow = tid >> 2, bc = tid & 3;
    for (int k0 = 0; k0 < 512; k0 += 64) {
        const _Float16* srca = X + (size_t)(r0 + arow) * 512 + k0 + ahf * 32;
#pragma unroll
        for (int c = 0; c < 4; ++c)
            *(half8*)&As[arow][ahf * 32 + c * 8] = *(const half8*)(srca + c * 8);
        const _Float16* srcb = W + (size_t)(j0 + brow) * 512 + k0 + bc * 16;
#pragma unroll
        for (int c = 0; c < 2; ++c)
            *(half8*)&Bs[brow][bc * 16 + c * 8] = *(const half8*)(srcb + c * 8);
        __syncthreads();
#pragma unroll
        for (int kt = 0; kt < 2; ++kt) {
            half8 bf0 = *(half8*)&Bs[32 * wc + l15][kt * 32 + g * 8];
            half8 bf1 = *(half8*)&Bs[32 * wc + 16 + l15][kt * 32 + g * 8];
#pragma unroll
            for (int ri = 0; ri < 4; ++ri) {
                half8 af = *(half8*)&As[64 * wr + 16 * ri + l15][kt * 32 + g * 8];
                acc[ri][0] = MFMA16(af, bf0, acc[ri][0]);
                acc[ri][1] = MFMA16(af, bf1, acc[ri][1]);
            }
        }
        __syncthreads();
    }
#pragma unroll
    for (int ri = 0; ri < 4; ++ri) {
#pragma unroll
        for (int cj = 0; cj < 2; ++cj) {
            const int col = j0 + 32 * wc + 16 * cj + l15;
            const int sec = col >> 9, hh = (col >> 6) & 7, d = col & 63;
            const float bv = bias[col];
#pragma unroll
            for (int r = 0; r < 4; ++r) {
                const int row = r0 + 64 * wr + 16 * ri + 4 * g + r;
                const int b = row & 3, s = row >> 2;
                const float v = acc[ri][cj][r];
                if (sec == 0)
                    Qo[((size_t)(b * 8 + hh) * 2048 + s) * 64 + d] = (_Float16)((v + bv) * 0.125f);
                else if (sec == 1)
                    Ko[((size_t)(b * 8 + hh) * 2048 + s) * 64 + d] = (_Float16)(v + bv);
                else {
                    const int ps = (s & ~31) | ((s & 12) << 1) | ((s & 16) >> 2) | (s & 3);
                    Vt[((size_t)(b * 8 + hh) * 64 + d) * 2048 + ps] = (_Float16)(v * gate[b] + bv);
                }
            }
        }
    }
}

// ---------------- K2: flash attention, batch-per-wave, LDS-shared mask ----------
// Block = (h, 128 q-rows, kv-HALF 1024), 512 threads, 1 block/CU, grid 256.
// Wave w: batch b = w&3, q-half qh = w>>2 -> 64 q-rows (qj=0..3). Each K/V
// fragment read feeds 4 MFMAs (reused across qj). Mask shared at block level
// via Mlds (staged with 256B-contiguous gll bursts). Best-known (R16).
__global__ __launch_bounds__(512) void attn_mfma(
    const _Float16* __restrict__ Q, const _Float16* __restrict__ K,
    const _Float16* __restrict__ V, const float* __restrict__ M,
    _Float16* __restrict__ P0, _Float16* __restrict__ P1, float* __restrict__ Lb)
{
    __shared__ _Float16 Kl[2][4][32][64];    // 32 KB
    __shared__ _Float16 Vl[2][4][64][32];    // 32 KB
    __shared__ float    Mlds[2][128][64];    // 64 KB  [buf][row][t-local in super]
    const int tid = threadIdx.x;
    const int lane = tid & 63, w = tid >> 6;
    const int l15 = lane & 15, g = lane >> 4;
    const int bid = blockIdx.x;
    const int kvh = bid & 1, h = (bid >> 1) & 7, qg = bid >> 4;
    const int b = w & 3, qh = w >> 2;
    const int q0 = qg * 128 + qh * 64;
    const size_t bh = (size_t)b * 8 + h;
    const _Float16* Qp = Q + bh * 2048 * 64;
    const _Float16* Kp = K + (bh * 2048 + (size_t)kvh * 1024) * 64;
    const _Float16* Vp = V + bh * 64 * 2048 + kvh * 1024;
    const float* Mp = M + (size_t)h * 2048 * 2048 + kvh * 1024;  // [q][t-local]

    // Q fragments: 64 q-rows of batch b
    half8 qf[4][2];
#pragma unroll
    for (int qj = 0; qj < 4; ++qj)
#pragma unroll
        for (int dh = 0; dh < 2; ++dh)
            qf[qj][dh] = *(const half8*)(Qp + (size_t)(q0 + 16 * qj + l15) * 64 + dh * 32 + g * 8);

    // K/V staging roles: wave w<4 stages K[b=w], w>=4 stages V[b=w-4]
    const bool stK = (w < 4);
    const int bs = w & 3;
    const int krow = lane >> 3, kblk = lane & 7;
    const int vrow = lane >> 2, vblk = lane & 3;
    const int ksw = (kblk ^ (krow & 7)) * 8;
    const int vsw = (vblk ^ ((vrow >> 1) & 3)) * 8;

    // mask staging lane mapping: one gll16 = 4 rows x 16 chunks (256 B/row burst)
    const int mrow_in = lane >> 4;   // 0..3
    const int mch = lane & 15;       // 16B chunk within row

    // prologue: K/V tile 0 -> buf0; mask super 0 -> Mlds[0]
    if (stK) {
#pragma unroll
        for (int c = 0; c < 4; ++c)
            gll16(Kp + (size_t)(c * 8 + krow) * 64 + ksw, &Kl[0][bs][c * 8][0]);
    } else {
#pragma unroll
        for (int c = 0; c < 4; ++c)
            gll16(Vp + (size_t)(c * 16 + vrow) * 2048 + vsw, &Vl[0][bs][c * 16][0]);
    }
#pragma unroll
    for (int c = 0; c < 4; ++c) {
        const int row = w * 16 + c * 4 + mrow_in;            // 0..127
        const int srcch = mch ^ (row & 7);
        gll16(Mp + (size_t)(qg * 128 + row) * 2048 + srcch * 4, &Mlds[0][w * 16 + c * 4][0]);
    }

    f32x4 O[4][4] = {};   // [di][qj]
    float l[4] = {0.f, 0.f, 0.f, 0.f};
    __syncthreads();

    const int msw = l15 & 7;           // read-side chunk XOR (row & 7 == l15 & 7)

    for (int tl = 0; tl < 32; ++tl) {
        const int cur = tl & 1;
        const int sup = tl >> 1, sub = tl & 1;
        const int mcur = sup & 1;
        // prefetch next K/V tile into buf^1
        if (tl < 31) {
            const int tg = (tl + 1) * 32;
            if (stK) {
#pragma unroll
                for (int c = 0; c < 4; ++c)
                    gll16(Kp + (size_t)(tg + c * 8 + krow) * 64 + ksw,
                          &Kl[cur ^ 1][bs][c * 8][0]);
            } else {
#pragma unroll
                for (int c = 0; c < 4; ++c)
                    gll16(Vp + (size_t)(c * 16 + vrow) * 2048 + tg + vsw,
                          &Vl[cur ^ 1][bs][c * 16][0]);
            }
        }
        // stage next mask super-tile (first subtile of each super)
        if (sub == 0 && tl < 30) {
            const int toff = (sup + 1) * 64;
#pragma unroll
            for (int c = 0; c < 4; ++c) {
                const int row = w * 16 + c * 4 + mrow_in;
                const int srcch = mch ^ (row & 7);
                gll16(Mp + (size_t)(qg * 128 + row) * 2048 + toff + srcch * 4,
                      &Mlds[mcur ^ 1][w * 16 + c * 4][0]);
            }
        }

        // QK^T: K fragments reused across 4 q-subtiles; mask C-init from Mlds
        f32x4 St[2][4];
#pragma unroll
        for (int mi = 0; mi < 2; ++mi) {
            const int row = 16 * mi + l15;
            half8 kf0 = *(half8*)&Kl[cur][b][row][((g) ^ (l15 & 7)) * 8];
            half8 kf1 = *(half8*)&Kl[cur][b][row][((4 + g) ^ (l15 & 7)) * 8];
#pragma unroll
            for (int qj = 0; qj < 4; ++qj) {
                const f32x4 ci = *(const f32x4*)
                    &Mlds[mcur][qh * 64 + 16 * qj + l15][((sub * 8 + mi * 4 + g) ^ msw) * 4];
                St[mi][qj] = MFMA16(kf0, qf[qj][0], ci);
                St[mi][qj] = MFMA16(kf1, qf[qj][1], St[mi][qj]);
            }
        }

        // static softmax partials + P fragments (split k-map {4g+j, 16+4g+(j-4)})
        half8 pf[4];
#pragma unroll
        for (int qj = 0; qj < 4; ++qj) {
            float e0 = __expf(St[0][qj][0]), e1 = __expf(St[0][qj][1]);
            float e2 = __expf(St[0][qj][2]), e3 = __expf(St[0][qj][3]);
            float e4 = __expf(St[1][qj][0]), e5 = __expf(St[1][qj][1]);
            float e6 = __expf(St[1][qj][2]), e7 = __expf(St[1][qj][3]);
            l[qj] += ((e0 + e1) + (e2 + e3)) + ((e4 + e5) + (e6 + e7));
            half8 pp;
            pp[0] = (_Float16)e0; pp[1] = (_Float16)e1; pp[2] = (_Float16)e2; pp[3] = (_Float16)e3;
            pp[4] = (_Float16)e4; pp[5] = (_Float16)e5; pp[6] = (_Float16)e6; pp[7] = (_Float16)e7;
            pf[qj] = pp;
        }

        // PV: V fragments reused across 4 q-subtiles
#pragma unroll
        for (int di = 0; di < 4; ++di) {
            const int row = 16 * di + l15;
            half8 vf = *(half8*)&Vl[cur][b][row][(g ^ ((l15 >> 1) & 3)) * 8];
#pragma unroll
            for (int qj = 0; qj < 4; ++qj)
                O[di][qj] = MFMA16(vf, pf[qj], O[di][qj]);
        }

        __syncthreads();   // drains vmcnt (gll K/V + mask) + LDS reads
    }

    // epilogue: per q-subtile, reduce l across g, write normalized partial + l
    _Float16* P = kvh ? P1 : P0;
#pragma unroll
    for (int qj = 0; qj < 4; ++qj) {
        float lt = l[qj];
        lt += __shfl_xor(lt, 16);
        lt += __shfl_xor(lt, 32);
        const float inv = 1.0f / lt;
        const int q = q0 + 16 * qj + l15;
        const int r = q * 4 + b;
        _Float16* dst = P + (size_t)r * 512 + h * 64;
#pragma unroll
        for (int di = 0; di < 4; ++di) {
            half4 o;
            o[0] = (_Float16)(O[di][qj][0] * inv); o[1] = (_Float16)(O[di][qj][1] * inv);
            o[2] = (_Float16)(O[di][qj][2] * inv); o[3] = (_Float16)(O[di][qj][3] * inv);
            *(half4*)(dst + 16 * di + 4 * g) = o;
        }
        if (g == 0)
            Lb[(size_t)kvh * 65536 + r * 8 + h] = lt;
    }
}

// ---------------- K2b: merge the two kv-half partials (raw-l weights) ------------
__global__ __launch_bounds__(256) void merge_attn(
    const _Float16* __restrict__ P0, const _Float16* __restrict__ P1,
    const float* __restrict__ Lb, _Float16* __restrict__ AO)
{
    const size_t e = ((size_t)blockIdx.x * 256 + threadIdx.x) * 8;
    const int r = (int)(e >> 9);
    const int h = (int)((e & 511) >> 6);
    const int li = r * 8 + h;
    const float l0 = Lb[li], l1 = Lb[65536 + li];
    const float inv = 1.0f / (l0 + l1);
    const float a0 = l0 * inv, a1 = l1 * inv;
    half8 x0 = *(const half8*)(P0 + e);
    half8 x1 = *(const half8*)(P1 + e);
    half8 o;
#pragma unroll
    for (int i = 0; i < 8; ++i)
        o[i] = (_Float16)(a0 * (float)x0[i] + a1 * (float)x1[i]);
    *(half8*)(AO + e) = o;
}

// ---------------- K3: output projection (f16 inputs, f32 out) ----------------
__global__ __launch_bounds__(256) void oproj_mfma(
    const _Float16* __restrict__ A, const _Float16* __restrict__ W,
    const float* __restrict__ bias, float* __restrict__ Out)
{
    __shared__ _Float16 As[128][72];
    __shared__ _Float16 Bs[64][72];
    const int tid = threadIdx.x;
    const int lane = tid & 63, wv = tid >> 6;
    const int l15 = lane & 15, g = lane >> 4;
    const int wr = wv >> 1, wc = wv & 1;
    const int j0 = blockIdx.x * 64, r0 = blockIdx.y * 128;
    f32x4 acc[4][2] = {};
    const int arow = tid >> 1, ahf = tid & 1;
    const int brow = tid >> 2, bc = tid & 3;
    for (int k0 = 0; k0 < 512; k0 += 64) {
        const _Float16* srca = A + (size_t)(r0 + arow) * 512 + k0 + ahf * 32;
#pragma unroll
        for (int c = 0; c < 4; ++c)
            *(half8*)&As[arow][ahf * 32 + c * 8] = *(const half8*)(srca + c * 8);
        const _Float16* srcb = W + (size_t)(j0 + brow) * 512 + k0 + bc * 16;
#pragma unroll
        for (int c = 0; c < 2; ++c)
            *(half8*)&Bs[brow][bc * 16 + c * 8] = *(const half8*)(srcb + c * 8);
        __syncthreads();
#pragma unroll
        for (int kt = 0; kt < 2; ++kt) {
            half8 bf0 = *(half8*)&Bs[32 * wc + l15][kt * 32 + g * 8];
            half8 bf1 = *(half8*)&Bs[32 * wc + 16 + l15][kt * 32 + g * 8];
#pragma unroll
            for (int ri = 0; ri < 4; ++ri) {
                half8 af = *(half8*)&As[64 * wr + 16 * ri + l15][kt * 32 + g * 8];
                acc[ri][0] = MFMA16(af, bf0, acc[ri][0]);
                acc[ri][1] = MFMA16(af, bf1, acc[ri][1]);
            }
        }
        __syncthreads();
    }
#pragma unroll
    for (int ri = 0; ri < 4; ++ri) {
#pragma unroll
        for (int cj = 0; cj < 2; ++cj) {
            const int col = j0 + 32 * wc + 16 * cj + l15;
            const float bv = bias[col];
#pragma unroll
            for (int r = 0; r < 4; ++r) {
                const int row = r0 + 64 * wr + 16 * ri + 4 * g + r;
                Out[(size_t)row * 512 + col] = acc[ri][cj][r] + bv;
            }
        }
    }
}

extern "C" void kernel_launch(void* const* d_in, const int* in_sizes, int n_in,
                              void* d_out, int out_size, void* d_ws, size_t ws_size,
                              hipStream_t stream)
{
    (void)in_sizes; (void)n_in; (void)out_size; (void)ws_size;
    const float* X    = (const float*)d_in[0];  // (S,B,D)
    const float* Mask = (const float*)d_in[1];  // (H,S,S)
    const float* gate = (const float*)d_in[2];  // (1,B,1)
    const float* Wi   = (const float*)d_in[3];  // (3D,D)
    const float* bi   = (const float*)d_in[4];  // (3D)
    const float* Wo   = (const float*)d_in[5];  // (D,D)
    const float* bo   = (const float*)d_in[6];  // (D)
    _Float16* ws = (_Float16*)d_ws;
    const size_t plane = (size_t)4 * 8 * 2048 * 64;  // 4,194,304 f16 elems
    _Float16* Qh  = ws;
    _Float16* Kh  = ws + plane;
    _Float16* Vt  = ws + 2 * plane;              // pre-permuted V^T
    _Float16* AO  = ws + 3 * plane;
    _Float16* Xh  = ws + 4 * plane;              // dead after qkv; aliased by P0
    _Float16* Wih = ws + 5 * plane;              // 786,432 (dead after qkv)
    _Float16* Woh = ws + 5 * plane + 786432;     // 262,144 (live until oproj)
    _Float16* P0  = Xh;
    _Float16* P1  = ws + 5 * plane + 1048576;
    float*    Lb  = (float*)(P1 + plane);        // 2*65536 f32

    cvt_f16<<<dim3(2560), 256, 0, stream>>>(X, Wi, Wo, Xh, Wih, Woh);
    qkv_mfma<<<dim3(24, 64), 256, 0, stream>>>(Xh, Wih, bi, gate, Qh, Kh, Vt);
    attn_mfma<<<dim3(256), 512, 0, stream>>>(Qh, Kh, Vt, Mask, P0, P1, Lb);
    merge_attn<<<dim3(2048), 256, 0, stream>>>(P0, P1, Lb, AO);
    oproj_mfma<<<dim3(8, 64), 256, 0, stream>>>(AO, Woh, bo, (float*)d_out);
}